// Round 1
// baseline (105.051 us; speedup 1.0000x reference)
//
#include <hip/hip_runtime.h>

// Bilateral filter denoiser: K=5, sigma_s=2.0, sigma_r=0.1, B=8,C=3,H=512,W=512, fp32.
// combined weight = exp(-(v-c)^2/(2*0.1^2)) * exp(-(dx^2+dy^2)/(2*2^2))
//                 = exp2( (v-c)^2 * RC + LS[dy][dx] )
// RC = -50*log2(e), LS = -(dx^2+dy^2)*log2(e)/8  (compile-time constants)

#define KK 5
#define HALO 2
#define TX 64          // tile width (pixels)
#define TY 16          // tile height
#define PXT 4          // pixels per thread along x
#define LW (TX + 2*HALO)   // 68
#define LH (TY + 2*HALO)   // 20
#define LSTRIDE (LW + 1)   // 69: row shift of 5 banks -> conflict-free reads
#define IMG_H 512
#define IMG_W 512

#if defined(__has_builtin)
#if __has_builtin(__builtin_amdgcn_exp2f)
#define FAST_EXP2(x) __builtin_amdgcn_exp2f(x)
#else
#define FAST_EXP2(x) exp2f(x)
#endif
#else
#define FAST_EXP2(x) exp2f(x)
#endif

__device__ __forceinline__ int reflect_idx(int i, int n) {
    i = (i < 0) ? -i : i;
    i = (i >= n) ? (2 * n - 2 - i) : i;
    return i;
}

__global__ __launch_bounds__(256, 4)
void bilateral_kernel(const float* __restrict__ x, float* __restrict__ out) {
    __shared__ float tile[LH * LSTRIDE];

    const int tid = threadIdx.x;
    const int tileX0 = blockIdx.x * TX;
    const int tileY0 = blockIdx.y * TY;
    const int img = blockIdx.z;
    const float* __restrict__ src = x + (size_t)img * (IMG_H * IMG_W);
    float* __restrict__ dst = out + (size_t)img * (IMG_H * IMG_W);

    // ---- stage halo tile into LDS with reflect padding ----
    for (int idx = tid; idx < LH * LW; idx += 256) {
        int r = idx / LW;
        int c = idx - r * LW;
        int gy = reflect_idx(tileY0 - HALO + r, IMG_H);
        int gx = reflect_idx(tileX0 - HALO + c, IMG_W);
        tile[r * LSTRIDE + c] = src[gy * IMG_W + gx];
    }
    __syncthreads();

    const int txg = tid & 15;      // thread x-group: 0..15
    const int ty  = tid >> 4;      // thread row:     0..15
    const int lx0 = txg * PXT;     // tile-local x of first pixel (halo frame)

    // centers (halo coords: +HALO in both axes)
    const float* crow = &tile[(ty + HALO) * LSTRIDE + lx0 + HALO];
    const float c0 = crow[0], c1 = crow[1], c2 = crow[2], c3 = crow[3];

    float acc0 = 0.f, acc1 = 0.f, acc2 = 0.f, acc3 = 0.f;
    float ws0 = 0.f, ws1 = 0.f, ws2 = 0.f, ws3 = 0.f;

    const float RC = -72.13475204444817f;     // -1/(2*0.1^2) * log2(e)
    const float SC = -0.18033688011246232f;   // -1/(2*2.0^2) * log2(e)

    #pragma unroll
    for (int dy = 0; dy < KK; dy++) {
        const float* r = &tile[(ty + dy) * LSTRIDE + lx0];
        float wrow[KK + PXT - 1];
        #pragma unroll
        for (int i = 0; i < KK + PXT - 1; i++) wrow[i] = r[i];

        const int dy2 = (dy - HALO) * (dy - HALO);
        #pragma unroll
        for (int dx = 0; dx < KK; dx++) {
            const float ls = SC * (float)((dx - HALO) * (dx - HALO) + dy2);
            {
                float v = wrow[dx + 0];
                float d = v - c0;
                float e = FAST_EXP2(fmaf(d * d, RC, ls));
                ws0 += e; acc0 = fmaf(e, v, acc0);
            }
            {
                float v = wrow[dx + 1];
                float d = v - c1;
                float e = FAST_EXP2(fmaf(d * d, RC, ls));
                ws1 += e; acc1 = fmaf(e, v, acc1);
            }
            {
                float v = wrow[dx + 2];
                float d = v - c2;
                float e = FAST_EXP2(fmaf(d * d, RC, ls));
                ws2 += e; acc2 = fmaf(e, v, acc2);
            }
            {
                float v = wrow[dx + 3];
                float d = v - c3;
                float e = FAST_EXP2(fmaf(d * d, RC, ls));
                ws3 += e; acc3 = fmaf(e, v, acc3);
            }
        }
    }

    const int ox = tileX0 + lx0;
    const int oy = tileY0 + ty;
    float4 o;
    o.x = acc0 / fmaxf(ws0, 1e-10f);
    o.y = acc1 / fmaxf(ws1, 1e-10f);
    o.z = acc2 / fmaxf(ws2, 1e-10f);
    o.w = acc3 / fmaxf(ws3, 1e-10f);
    *reinterpret_cast<float4*>(&dst[oy * IMG_W + ox]) = o;
}

extern "C" void kernel_launch(void* const* d_in, const int* in_sizes, int n_in,
                              void* d_out, int out_size, void* d_ws, size_t ws_size,
                              hipStream_t stream) {
    const float* x = (const float*)d_in[0];
    // d_in[1] (spatial 5x5) is analytically exp(-(dx^2+dy^2)/8); folded into
    // compile-time log2 constants in the kernel.
    float* out = (float*)d_out;

    const int n_img = out_size / (IMG_H * IMG_W);   // B*C = 24
    dim3 grid(IMG_W / TX, IMG_H / TY, n_img);       // (8, 32, 24)
    dim3 block(256);
    hipLaunchKernelGGL(bilateral_kernel, grid, block, 0, stream, x, out);
}

// Round 2
// 101.663 us; speedup vs baseline: 1.0333x; 1.0333x over previous
//
#include <hip/hip_runtime.h>

// Bilateral filter denoiser: K=5, sigma_s=2.0, sigma_r=0.1, B=8,C=3,H=512,W=512, fp32.
// weight(dy,dx) = exp(-(n-c)^2/(2*0.1^2)) * exp(-(dx^2+dy^2)/8)
//              = exp2(RC*(n-c)^2) * STBL[dx^2+dy^2]
// RC*(n-c)^2 computed as fma(fma(RC,n,B), n, C0), B=-2RC*c, C0=RC*c^2 (2 FMAs/tap).
// 4 px/thread processed as two float2 halves -> v_pk_* packed fp32 ops.
// Center tap: weight == 1 exactly -> ws init 1, acc init c; ws>=1 so no clip, rcp ok.

#define KK 5
#define HALO 2
#define TX 64          // tile width (pixels)
#define TY 16          // tile height
#define PXT 4          // pixels per thread along x
#define LW (TX + 2*HALO)   // 68
#define LH (TY + 2*HALO)   // 20
#define LSTRIDE (LW + 1)   // 69: row shift of 5 banks, <=2-way b32 conflicts
#define IMG_H 512
#define IMG_W 512

typedef float v2f __attribute__((ext_vector_type(2)));

#if defined(__has_builtin)
#if __has_builtin(__builtin_amdgcn_exp2f)
#define FAST_EXP2(x) __builtin_amdgcn_exp2f(x)
#else
#define FAST_EXP2(x) exp2f(x)
#endif
#if __has_builtin(__builtin_amdgcn_rcpf)
#define FAST_RCP(x) __builtin_amdgcn_rcpf(x)
#else
#define FAST_RCP(x) (1.0f / (x))
#endif
#else
#define FAST_EXP2(x) exp2f(x)
#define FAST_RCP(x) (1.0f / (x))
#endif

__device__ __forceinline__ int reflect_idx(int i, int n) {
    i = (i < 0) ? -i : i;
    i = (i >= n) ? (2 * n - 2 - i) : i;
    return i;
}

__global__ __launch_bounds__(256, 4)
void bilateral_kernel(const float* __restrict__ x, float* __restrict__ out) {
    __shared__ float tile[LH * LSTRIDE];

    const int tid = threadIdx.x;
    const int tileX0 = blockIdx.x * TX;
    const int tileY0 = blockIdx.y * TY;
    const int img = blockIdx.z;
    const float* __restrict__ src = x + (size_t)img * (IMG_H * IMG_W);
    float* __restrict__ dst = out + (size_t)img * (IMG_H * IMG_W);

    // ---- stage halo tile into LDS with reflect padding ----
    for (int idx = tid; idx < LH * LW; idx += 256) {
        int r = idx / LW;
        int c = idx - r * LW;
        int gy = reflect_idx(tileY0 - HALO + r, IMG_H);
        int gx = reflect_idx(tileX0 - HALO + c, IMG_W);
        tile[r * LSTRIDE + c] = src[gy * IMG_W + gx];
    }
    __syncthreads();

    const int txg = tid & 15;      // thread x-group: 0..15
    const int ty  = tid >> 4;      // thread row:     0..15
    const int lx0 = txg * PXT;     // tile-local x of first pixel (halo frame)

    // spatial weights s = exp(-(dx^2+dy^2)/8), indexed by dx^2+dy^2 in {0,1,2,4,5,8}
    const float STBL_1 = 0.8824969025845955f;   // e^-0.125
    const float STBL_2 = 0.7788007830714049f;   // e^-0.25
    const float STBL_4 = 0.6065306597126334f;   // e^-0.5
    const float STBL_5 = 0.5352614285189903f;   // e^-0.625
    const float STBL_8 = 0.36787944117144233f;  // e^-1

    const float RC = -72.13475204444817f;       // -1/(2*0.1^2) * log2(e)
    const v2f RCv = {RC, RC};

    // center values (halo coords: +HALO both axes)
    const float* crow = &tile[(ty + HALO) * LSTRIDE + lx0 + HALO];
    const v2f cA = {crow[0], crow[1]};
    const v2f cB = {crow[2], crow[3]};

    // per-pixel exponent-poly coefficients: arg = RC*n^2 + B*n + C0
    const v2f BA = cA * (-2.0f * RC);
    const v2f BB = cB * (-2.0f * RC);
    const v2f C0A = (cA * cA) * RC;
    const v2f C0B = (cB * cB) * RC;

    // center tap folded in: weight exactly 1
    v2f wsA = {1.0f, 1.0f}, wsB = {1.0f, 1.0f};
    v2f accA = cA, accB = cB;

    auto tap = [&](v2f nA, v2f nB, float s) {
        v2f uA = __builtin_elementwise_fma(RCv, nA, BA);
        v2f tA = __builtin_elementwise_fma(uA, nA, C0A);
        v2f uB = __builtin_elementwise_fma(RCv, nB, BB);
        v2f tB = __builtin_elementwise_fma(uB, nB, C0B);
        v2f eA, eB;
        eA.x = FAST_EXP2(tA.x); eA.y = FAST_EXP2(tA.y);
        eB.x = FAST_EXP2(tB.x); eB.y = FAST_EXP2(tB.y);
        v2f fA = eA * s;
        v2f fB = eB * s;
        wsA += fA;
        wsB += fB;
        accA = __builtin_elementwise_fma(fA, nA, accA);
        accB = __builtin_elementwise_fma(fB, nB, accB);
    };

    #pragma unroll
    for (int dy = 0; dy < KK; dy++) {
        const float* r = &tile[(ty + dy) * LSTRIDE + lx0];
        // aligned pairs of the 8-float window
        v2f P0 = {r[0], r[1]};
        v2f P1 = {r[2], r[3]};
        v2f P2 = {r[4], r[5]};
        v2f P3 = {r[6], r[7]};
        // odd (crossing) pairs
        v2f O0 = __builtin_shufflevector(P0, P1, 1, 2);
        v2f O1 = __builtin_shufflevector(P1, P2, 1, 2);
        v2f O2 = __builtin_shufflevector(P2, P3, 1, 2);

        const float s4 = (dy == 0 || dy == 4) ? STBL_8 : (dy == 1 || dy == 3) ? STBL_5 : STBL_4;
        const float s1 = (dy == 0 || dy == 4) ? STBL_5 : (dy == 1 || dy == 3) ? STBL_2 : STBL_1;
        const float s0 = (dy == 0 || dy == 4) ? STBL_4 : STBL_1;  // dy==2 center handled below

        tap(P0, P1, s4);   // dx = 0
        tap(O0, O1, s1);   // dx = 1
        if (dy != 2) {
            tap(P1, P2, s0);  // dx = 2 (non-center rows)
        }
        tap(O1, O2, s1);   // dx = 3
        tap(P2, P3, s4);   // dx = 4
    }

    const int ox = tileX0 + lx0;
    const int oy = tileY0 + ty;
    float4 o;
    o.x = accA.x * FAST_RCP(wsA.x);   // ws >= 1 (center tap), clip(1e-10) is dead
    o.y = accA.y * FAST_RCP(wsA.y);
    o.z = accB.x * FAST_RCP(wsB.x);
    o.w = accB.y * FAST_RCP(wsB.y);
    *reinterpret_cast<float4*>(&dst[oy * IMG_W + ox]) = o;
}

extern "C" void kernel_launch(void* const* d_in, const int* in_sizes, int n_in,
                              void* d_out, int out_size, void* d_ws, size_t ws_size,
                              hipStream_t stream) {
    const float* x = (const float*)d_in[0];
    // d_in[1] (spatial 5x5) is analytically exp(-(dx^2+dy^2)/8); folded into constants.
    float* out = (float*)d_out;

    const int n_img = out_size / (IMG_H * IMG_W);   // B*C = 24
    dim3 grid(IMG_W / TX, IMG_H / TY, n_img);       // (8, 32, 24)
    dim3 block(256);
    hipLaunchKernelGGL(bilateral_kernel, grid, block, 0, stream, x, out);
}